// Round 11
// baseline (42.862 us; speedup 1.0000x reference)
//
#include <hip/hip_runtime.h>
#include <hip/hip_bf16.h>

// SkeletalConv via MFMA + LDS staging, single fused kernel, 4-chunk
// software pipeline (async-STAGE split: issue next chunk's global loads
// before computing the current chunk).
// x: (16, 25, 65536) f32, W: (48, 16, 16, 3) f32, b: (48, 16) f32
// out: (16, 24, 65534) f32
// out[co,e,t] = 0.5*sum_{j,ci,k} W[2e+j,co,ci,k]*x[ci,e+j,t+k] + 0.5*(b[2e,co]+b[2e+1,co])
//
// Per edge, K-dim kk=(ci,j) is 32 = one mfma_f32_16x16x32_bf16 per tap.
// lds[ci][col] = dword(bf16 x[ci,e,col] | bf16 x[ci,e+1,col]<<16) = B-frag
// slot dword. A = W-frag per lane (co=l&15, slots kk=8g+i), built from 6
// aligned float4 loads (L2-hot). C row = co = 4g+r, col = t -> coalesced
// dword stores (round 9: swapped operands scatter stores, 46->53us).
// Epilogue: out = 0.5*C + 0.5*(b[2e,co]+b[2e+1,co]).

#define NJ    25
#define LSEQ  65536
#define NE    24
#define LOUTN (LSEQ - 2)               // 65534 valid t
#define CW    260                      // LDS row width in dwords
#define CPB   4                        // chunks (256 cols) per block

typedef __attribute__((ext_vector_type(8))) short bf16x8;
typedef __attribute__((ext_vector_type(4))) float f32x4;

static __device__ __forceinline__ unsigned cvtpk(float lo, float hi) {
    union { __hip_bfloat162 h; unsigned u; } cv;
    cv.h = __float22bfloat162_rn(make_float2(lo, hi));   // v_cvt_pk_bf16_f32
    return cv.u;
}

__global__ __launch_bounds__(256)
void skel_mfma_kernel(const float* __restrict__ x,
                      const float* __restrict__ W,
                      const float* __restrict__ b,
                      float* __restrict__ out)
{
    __shared__ unsigned lds[16 * CW];   // [ci][col] bf16 pair (joint e | e+1)

    const int e   = blockIdx.y;
    const int cb0 = blockIdx.x * (CPB * 256);   // base col of this block
    const int tid = threadIdx.x;
    const int l   = tid & 63, wv = tid >> 6;
    const int g   = l >> 4,  lc = l & 15;

    // ---- A fragments (W): lane l -> co=lc, slots kk=8g+i, 3 taps ----
    const float* wp = W + ((size_t)((2 * e) * 16 + lc) * 16 + 4 * g) * 3;
    f32x4 wj0[3], wj1[3];
    #pragma unroll
    for (int q = 0; q < 3; ++q) {
        wj0[q] = *reinterpret_cast<const f32x4*>(wp + 4 * q);
        wj1[q] = *reinterpret_cast<const f32x4*>(wp + 768 + 4 * q);
    }
    union { unsigned u[4]; bf16x8 v8; } Aw[3];
    #pragma unroll
    for (int d = 0; d < 4; ++d)
        #pragma unroll
        for (int k = 0; k < 3; ++k) {
            const int f = d * 3 + k;            // compile-time after unroll
            Aw[k].u[d] = cvtpk(wj0[f >> 2][f & 3], wj1[f >> 2][f & 3]);
        }

    // ---- folded bias for rows co = 4g+r ----
    const f32x4 b0 = *reinterpret_cast<const f32x4*>(b + (size_t)(2 * e) * 16 + 4 * g);
    const f32x4 b1 = *reinterpret_cast<const f32x4*>(b + (size_t)(2 * e + 1) * 16 + 4 * g);
    f32x4 bias;
    #pragma unroll
    for (int r = 0; r < 4; ++r) bias[r] = 0.5f * (b0[r] + b1[r]);

    // ---- staging assignments ----
    const int rp = tid >> 4;                    // ci row
    const int q0 = tid & 15;
    const float* xrow = x + (size_t)(rp * NJ + e) * LSEQ;      // joint e (+LSEQ = e+1)
    const int hrp = tid >> 1, hh = tid & 1;     // halo (tid<32)
    const float* xh = x + (size_t)(hrp * NJ + e) * LSEQ;

    float4 PL[4], PH[4];                        // prefetch regs
    float hl0 = 0.f, hl1 = 0.f;                 // halo pair

    auto issue_loads = [&](int tb) {
        const float* xlo = xrow + tb;
        #pragma unroll
        for (int s = 0; s < 4; ++s) {
            const int c = 4 * q0 + 64 * s;      // 16B-aligned, never OOB (tb+255<=65535)
            PL[s] = *reinterpret_cast<const float4*>(xlo + c);
            PH[s] = *reinterpret_cast<const float4*>(xlo + LSEQ + c);
        }
        if (tid < 32) {
            const int gc = min(tb + 256 + hh, LSEQ - 1);   // clamp (last chunk only)
            hl0 = xh[gc]; hl1 = xh[gc + LSEQ];
        }
    };

    auto write_lds = [&]() {
        #pragma unroll
        for (int s = 0; s < 4; ++s) {
            const int c = 4 * q0 + 64 * s;
            uint4 pk;
            pk.x = cvtpk(PL[s].x, PH[s].x);
            pk.y = cvtpk(PL[s].y, PH[s].y);
            pk.z = cvtpk(PL[s].z, PH[s].z);
            pk.w = cvtpk(PL[s].w, PH[s].w);
            *reinterpret_cast<uint4*>(&lds[rp * CW + c]) = pk;
        }
        if (tid < 32) lds[hrp * CW + 256 + hh] = cvtpk(hl0, hl1);
    };

    issue_loads(cb0);

    #pragma unroll
    for (int cc = 0; cc < CPB; ++cc) {
        const int tb = cb0 + cc * 256;

        write_lds();
        __syncthreads();

        if (cc + 1 < CPB) issue_loads(tb + 256);   // fly under compute

        #pragma unroll
        for (int tc = 0; tc < 4; ++tc) {
            const int cb = wv * 64 + tc * 16 + lc;  // col within chunk
            f32x4 C = {0.f, 0.f, 0.f, 0.f};
            #pragma unroll
            for (int k = 0; k < 3; ++k) {
                union { unsigned u[4]; bf16x8 v8; } Bx;
                #pragma unroll
                for (int d = 0; d < 4; ++d)
                    Bx.u[d] = lds[(4 * g + d) * CW + cb + k];
                C = __builtin_amdgcn_mfma_f32_16x16x32_bf16(Aw[k].v8, Bx.v8, C, 0, 0, 0);
            }
            const int t = tb + cb;
            if (t < LOUTN) {
                #pragma unroll
                for (int r = 0; r < 4; ++r)
                    out[(size_t)((4 * g + r) * NE + e) * LOUTN + t] = fmaf(0.5f, C[r], bias[r]);
            }
        }

        if (cc + 1 < CPB) __syncthreads();          // LDS reuse fence
    }
}

extern "C" void kernel_launch(void* const* d_in, const int* in_sizes, int n_in,
                              void* d_out, int out_size, void* d_ws, size_t ws_size,
                              hipStream_t stream)
{
    const float* x = (const float*)d_in[0];
    const float* W = (const float*)d_in[1];
    const float* b = (const float*)d_in[2];
    float* out     = (float*)d_out;

    dim3 grid((LOUTN + CPB * 256 - 1) / (CPB * 256), NE);   // 64 x 24 blocks
    skel_mfma_kernel<<<grid, 256, 0, stream>>>(x, W, b, out);
}

// Round 12
// 41.017 us; speedup vs baseline: 1.0450x; 1.0450x over previous
//
#include <hip/hip_runtime.h>
#include <hip/hip_bf16.h>

// SkeletalConv via MFMA + LDS staging + LDS-transpose aligned-store epilogue.
// x: (16, 25, 65536) f32, W: (48, 16, 16, 3) f32, b: (48, 16) f32
// out: (16, 24, 65534) f32
// out[co,e,t] = 0.5*sum_{j,ci,k} W[2e+j,co,ci,k]*x[ci,e+j,t+k] + 0.5*(b[2e,co]+b[2e+1,co])
//
// Math path = round 10 (best, 42.9us): lds[ci][col] = dword(bf16 x[ci,e,col],
// bf16 x[ci,e+1,col]) = B-frag slot dword; A = W-frag per lane (6 aligned
// float4 loads); one mfma_f32_16x16x32_bf16 per tap; C row=co, col=t.
// NEW epilogue: C -> LDS [co][col] tile (aliases staging, barrier-separated),
// then each thread owns one co-row and stores 5 predicated float4s whose
// addresses are 64B-line-aligned in that row's frame (srow phase shift).
// Rationale: round-10/11 counters show WRITE_SIZE 115MB vs 100.7MB output --
// partial-line writes at every chunk boundary (rows are 65534 floats, never
// line-aligned; neighbor chunks sit on different XCD L2s) cause write-
// allocate RMW. Aligned full-line stores remove ~25MB of HBM traffic.

#define NJ    25
#define LSEQ  65536
#define NE    24
#define LOUTN (LSEQ - 2)               // 65534 valid t
#define CW    260                      // staging row stride (dwords)
#define CWT   292                      // C-tile row stride (dwords), mult of 4
#define LDSN  (64 + 16 * CWT)          // +64 front pad for safe underreads

typedef __attribute__((ext_vector_type(8))) short bf16x8;
typedef __attribute__((ext_vector_type(4))) float f32x4;

static __device__ __forceinline__ unsigned cvtpk(float lo, float hi) {
    union { __hip_bfloat162 h; unsigned u; } cv;
    cv.h = __float22bfloat162_rn(make_float2(lo, hi));   // v_cvt_pk_bf16_f32
    return cv.u;
}

__global__ __launch_bounds__(256)
void skel_mfma_kernel(const float* __restrict__ x,
                      const float* __restrict__ W,
                      const float* __restrict__ b,
                      float* __restrict__ out)
{
    __shared__ unsigned lds[LDSN];      // staging tile, later aliased as C tile

    const int e   = blockIdx.y;
    const int tb  = blockIdx.x * 256;
    const int tid = threadIdx.x;
    const int l   = tid & 63, wv = tid >> 6;
    const int g   = l >> 4,  lc = l & 15;

    // ---- A fragments (W): lane l -> co=lc, slots kk=8g+i, 3 taps ----
    const float* wp = W + ((size_t)((2 * e) * 16 + lc) * 16 + 4 * g) * 3;
    f32x4 wj0[3], wj1[3];
    #pragma unroll
    for (int q = 0; q < 3; ++q) {
        wj0[q] = *reinterpret_cast<const f32x4*>(wp + 4 * q);
        wj1[q] = *reinterpret_cast<const f32x4*>(wp + 768 + 4 * q);
    }
    union { unsigned u[4]; bf16x8 v8; } Aw[3];
    #pragma unroll
    for (int d = 0; d < 4; ++d)
        #pragma unroll
        for (int k = 0; k < 3; ++k) {
            const int f = d * 3 + k;            // compile-time after unroll
            Aw[k].u[d] = cvtpk(wj0[f >> 2][f & 3], wj1[f >> 2][f & 3]);
        }

    // ---- folded bias for rows co = 4g+r ----
    const f32x4 b0 = *reinterpret_cast<const f32x4*>(b + (size_t)(2 * e) * 16 + 4 * g);
    const f32x4 b1 = *reinterpret_cast<const f32x4*>(b + (size_t)(2 * e + 1) * 16 + 4 * g);
    f32x4 bias;
    #pragma unroll
    for (int r = 0; r < 4; ++r) bias[r] = 0.5f * (b0[r] + b1[r]);

    // ---- stage: 16 ci-rows x 256 cols (+2 halo) ----
    {
        const int rp = tid >> 4;                    // ci
        const int q0 = tid & 15;
        const float* xlo = x + (size_t)(rp * NJ + e) * LSEQ + tb;
        #pragma unroll
        for (int s = 0; s < 4; ++s) {
            const int c = 4 * q0 + 64 * s;          // 16B-aligned, never OOB
            float4 lo = *reinterpret_cast<const float4*>(xlo + c);
            float4 hi = *reinterpret_cast<const float4*>(xlo + LSEQ + c);
            uint4 pk;
            pk.x = cvtpk(lo.x, hi.x);
            pk.y = cvtpk(lo.y, hi.y);
            pk.z = cvtpk(lo.z, hi.z);
            pk.w = cvtpk(lo.w, hi.w);
            *reinterpret_cast<uint4*>(&lds[rp * CW + c]) = pk;
        }
    }
    if (tid < 32) {                                 // halo cols 256,257
        const int rp = tid >> 1, h = tid & 1;
        const int gc = min(tb + 256 + h, LSEQ - 1); // clamp (last chunk only)
        const float* xl = x + (size_t)(rp * NJ + e) * LSEQ;
        lds[rp * CW + 256 + h] = cvtpk(xl[gc], xl[gc + LSEQ]);
    }
    __syncthreads();

    // ---- compute: wave wv owns cols wv*64..wv*64+63; keep C in regs ----
    f32x4 C[4];
    #pragma unroll
    for (int tc = 0; tc < 4; ++tc) {
        const int cb = wv * 64 + tc * 16 + lc;      // col within chunk
        f32x4 acc = {0.f, 0.f, 0.f, 0.f};
        #pragma unroll
        for (int k = 0; k < 3; ++k) {
            union { unsigned u[4]; bf16x8 v8; } Bx;
            #pragma unroll
            for (int d = 0; d < 4; ++d)
                Bx.u[d] = lds[(4 * g + d) * CW + cb + k];
            acc = __builtin_amdgcn_mfma_f32_16x16x32_bf16(Aw[k].v8, Bx.v8, acc, 0, 0, 0);
        }
        C[tc] = acc;
    }
    __syncthreads();                                // staging reads complete

    // ---- epilogue 1: final values -> LDS C-tile [co][col] ----
    {
        float* cl = reinterpret_cast<float*>(lds);
        int srw[4];
        #pragma unroll
        for (int r = 0; r < 4; ++r) {
            const int row = 4 * g + r;              // co
            const size_t rb = (size_t)(row * NE + e) * LOUTN + tb;
            srw[r] = (int)((16 - (rb & 15)) & 15);  // row alignment phase
        }
        #pragma unroll
        for (int tc = 0; tc < 4; ++tc) {
            const int cb = wv * 64 + tc * 16 + lc;
            #pragma unroll
            for (int r = 0; r < 4; ++r)
                cl[64 + (4 * g + r) * CWT + 16 + cb - srw[r]] = fmaf(0.5f, C[tc][r], bias[r]);
        }
    }
    __syncthreads();                                // C-tile complete

    // ---- epilogue 2: per-row 64B-aligned float4 stores ----
    {
        const float* cl = reinterpret_cast<const float*>(lds);
        const int row = tid >> 4;                   // co
        const int q   = tid & 15;
        const size_t rbase = (size_t)(row * NE + e) * LOUTN;
        const int srow = (int)((16 - ((rbase + tb) & 15)) & 15);
        #pragma unroll
        for (int s = 0; s < 5; ++s) {
            const int col = srow - 64 + 64 * s + 4 * q;   // block-frame col
            // LDS index = 64 + row*CWT + 16 + (col - srow): 16B-aligned
            const f32x4 v = *reinterpret_cast<const f32x4*>(
                cl + 64 + row * CWT - 48 + 64 * s + 4 * q);
            const long t = (long)tb + col;
            if (col >= 0 && col + 3 < 256 && t + 3 < LOUTN) {
                *reinterpret_cast<f32x4*>(out + rbase + t) = v;   // full line
            } else {
                #pragma unroll
                for (int d = 0; d < 4; ++d)
                    if (col + d >= 0 && col + d < 256 && t + d < LOUTN)
                        out[rbase + t + d] = v[d];
            }
        }
    }
}

extern "C" void kernel_launch(void* const* d_in, const int* in_sizes, int n_in,
                              void* d_out, int out_size, void* d_ws, size_t ws_size,
                              hipStream_t stream)
{
    const float* x = (const float*)d_in[0];
    const float* W = (const float*)d_in[1];
    const float* b = (const float*)d_in[2];
    float* out     = (float*)d_out;

    dim3 grid((LOUTN + 255) / 256, NE);      // 256 x 24 blocks, single launch
    skel_mfma_kernel<<<grid, 256, 0, stream>>>(x, W, b, out);
}

// Round 13
// 40.730 us; speedup vs baseline: 1.0523x; 1.0070x over previous
//
#include <hip/hip_runtime.h>
#include <hip/hip_bf16.h>

// SkeletalConv via MFMA + LDS staging (fragment-contiguous layout) +
// LDS-transpose aligned-store epilogue.
// x: (16, 25, 65536) f32, W: (48, 16, 16, 3) f32, b: (48, 16) f32
// out: (16, 24, 65534) f32
// out[co,e,t] = 0.5*sum_{j,ci,k} W[2e+j,co,ci,k]*x[ci,e+j,t+k] + 0.5*(b[2e,co]+b[2e+1,co])
//
// Staging layout lds[q][col][d], q=ci>>2, d=ci&3: the 4 dwords of a
// B-fragment (ci=4g..4g+3 at one col) are contiguous 16B -> one
// ds_read_b128 per (tile,tap) instead of 4 ds_read_b32 (48->12 DS reads;
// round-12 audit showed these dominate the barrier->MFMA critical path).
// Staging: thread=(quad,col), 32 coalesced dword loads + 4 contiguous
// b128 writes (16-lane quarters cover 256 contiguous B -> conflict-free).
// A = W-frag per lane (co=l&15, slots kk=8g+i) from 6 aligned float4
// loads. C row=co, col=t. Epilogue (round 12, validated): C -> LDS
// [co][col] tile, then per-row 64B-aligned float4 stores (WRITE_SIZE
// 115->101MB, removed partial-line RMW).

#define NJ    25
#define LSEQ  65536
#define NE    24
#define LOUTN (LSEQ - 2)               // 65534 valid t
#define CQ    258                      // staging cols per quad (256 + 2 halo)
#define CWT   292                      // C-tile row stride (dwords), mult of 4
#define LDSN  (64 + 16 * CWT)          // 4736 dwords = 18944 B (>= staging 4128)

typedef __attribute__((ext_vector_type(8))) short bf16x8;
typedef __attribute__((ext_vector_type(4))) float f32x4;

static __device__ __forceinline__ unsigned cvtpk(float lo, float hi) {
    union { __hip_bfloat162 h; unsigned u; } cv;
    cv.h = __float22bfloat162_rn(make_float2(lo, hi));   // v_cvt_pk_bf16_f32
    return cv.u;
}

__global__ __launch_bounds__(256)
void skel_mfma_kernel(const float* __restrict__ x,
                      const float* __restrict__ W,
                      const float* __restrict__ b,
                      float* __restrict__ out)
{
    __shared__ unsigned lds[LDSN];      // staging tile, later aliased as C tile

    const int e   = blockIdx.y;
    const int tb  = blockIdx.x * 256;
    const int tid = threadIdx.x;
    const int l   = tid & 63, wv = tid >> 6;
    const int g   = l >> 4,  lc = l & 15;

    // ---- A fragments (W): lane l -> co=lc, slots kk=8g+i, 3 taps ----
    const float* wp = W + ((size_t)((2 * e) * 16 + lc) * 16 + 4 * g) * 3;
    f32x4 wj0[3], wj1[3];
    #pragma unroll
    for (int q = 0; q < 3; ++q) {
        wj0[q] = *reinterpret_cast<const f32x4*>(wp + 4 * q);
        wj1[q] = *reinterpret_cast<const f32x4*>(wp + 768 + 4 * q);
    }
    union { unsigned u[4]; bf16x8 v8; } Aw[3];
    #pragma unroll
    for (int d = 0; d < 4; ++d)
        #pragma unroll
        for (int k = 0; k < 3; ++k) {
            const int f = d * 3 + k;            // compile-time after unroll
            Aw[k].u[d] = cvtpk(wj0[f >> 2][f & 3], wj1[f >> 2][f & 3]);
        }

    // ---- folded bias for rows co = 4g+r ----
    const f32x4 b0 = *reinterpret_cast<const f32x4*>(b + (size_t)(2 * e) * 16 + 4 * g);
    const f32x4 b1 = *reinterpret_cast<const f32x4*>(b + (size_t)(2 * e + 1) * 16 + 4 * g);
    f32x4 bias;
    #pragma unroll
    for (int r = 0; r < 4; ++r) bias[r] = 0.5f * (b0[r] + b1[r]);

    // ---- stage: thread = (quad qs, col cs); 32 coalesced dword loads ----
    {
        const int qs = tid >> 6;                // quad (= wave)
        const int cs = tid & 63;
        const float* xr0 = x + (size_t)((4 * qs + 0) * NJ + e) * LSEQ + tb;
        const float* xr1 = x + (size_t)((4 * qs + 1) * NJ + e) * LSEQ + tb;
        const float* xr2 = x + (size_t)((4 * qs + 2) * NJ + e) * LSEQ + tb;
        const float* xr3 = x + (size_t)((4 * qs + 3) * NJ + e) * LSEQ + tb;
        #pragma unroll
        for (int s = 0; s < 4; ++s) {
            const int col = 64 * s + cs;        // never OOB (tb+255 <= 65535)
            uint4 pk;
            pk.x = cvtpk(xr0[col], xr0[col + LSEQ]);
            pk.y = cvtpk(xr1[col], xr1[col + LSEQ]);
            pk.z = cvtpk(xr2[col], xr2[col + LSEQ]);
            pk.w = cvtpk(xr3[col], xr3[col + LSEQ]);
            *reinterpret_cast<uint4*>(&lds[(qs * CQ + col) * 4]) = pk;
        }
    }
    if (tid < 32) {                             // halo cols 256,257 (all 16 ci)
        const int ci = tid >> 1, h = tid & 1;
        const int gc = min(tb + 256 + h, LSEQ - 1); // clamp (last chunk only)
        const float* xl = x + (size_t)(ci * NJ + e) * LSEQ;
        lds[((ci >> 2) * CQ + 256 + h) * 4 + (ci & 3)] = cvtpk(xl[gc], xl[gc + LSEQ]);
    }
    __syncthreads();

    // ---- compute: wave wv owns cols wv*64..wv*64+63; keep C in regs ----
    f32x4 C[4];
    #pragma unroll
    for (int tc = 0; tc < 4; ++tc) {
        const int cb = wv * 64 + tc * 16 + lc;      // col within chunk
        f32x4 acc = {0.f, 0.f, 0.f, 0.f};
        #pragma unroll
        for (int k = 0; k < 3; ++k) {
            union { uint4 q4; bf16x8 v8; } Bx;     // one b128 = whole fragment
            Bx.q4 = *reinterpret_cast<const uint4*>(&lds[(g * CQ + cb + k) * 4]);
            acc = __builtin_amdgcn_mfma_f32_16x16x32_bf16(Aw[k].v8, Bx.v8, acc, 0, 0, 0);
        }
        C[tc] = acc;
    }
    __syncthreads();                                // staging reads complete

    // ---- epilogue 1: final values -> LDS C-tile [co][col] ----
    {
        float* cl = reinterpret_cast<float*>(lds);
        int srw[4];
        #pragma unroll
        for (int r = 0; r < 4; ++r) {
            const int row = 4 * g + r;              // co
            const size_t rb = (size_t)(row * NE + e) * LOUTN + tb;
            srw[r] = (int)((16 - (rb & 15)) & 15);  // row alignment phase
        }
        #pragma unroll
        for (int tc = 0; tc < 4; ++tc) {
            const int cb = wv * 64 + tc * 16 + lc;
            #pragma unroll
            for (int r = 0; r < 4; ++r)
                cl[64 + (4 * g + r) * CWT + 16 + cb - srw[r]] = fmaf(0.5f, C[tc][r], bias[r]);
        }
    }
    __syncthreads();                                // C-tile complete

    // ---- epilogue 2: per-row 64B-aligned float4 stores ----
    {
        const float* cl = reinterpret_cast<const float*>(lds);
        const int row = tid >> 4;                   // co
        const int q   = tid & 15;
        const size_t rbase = (size_t)(row * NE + e) * LOUTN;
        const int srow = (int)((16 - ((rbase + tb) & 15)) & 15);
        #pragma unroll
        for (int s = 0; s < 5; ++s) {
            const int col = srow - 64 + 64 * s + 4 * q;   // block-frame col
            const f32x4 v = *reinterpret_cast<const f32x4*>(
                cl + 64 + row * CWT - 48 + 64 * s + 4 * q);
            const long t = (long)tb + col;
            if (col >= 0 && col + 3 < 256 && t + 3 < LOUTN) {
                *reinterpret_cast<f32x4*>(out + rbase + t) = v;   // full line
            } else {
                #pragma unroll
                for (int d = 0; d < 4; ++d)
                    if (col + d >= 0 && col + d < 256 && t + d < LOUTN)
                        out[rbase + t + d] = v[d];
            }
        }
    }
}

extern "C" void kernel_launch(void* const* d_in, const int* in_sizes, int n_in,
                              void* d_out, int out_size, void* d_ws, size_t ws_size,
                              hipStream_t stream)
{
    const float* x = (const float*)d_in[0];
    const float* W = (const float*)d_in[1];
    const float* b = (const float*)d_in[2];
    float* out     = (float*)d_out;

    dim3 grid((LOUTN + 255) / 256, NE);      // 256 x 24 blocks, single launch
    skel_mfma_kernel<<<grid, 256, 0, stream>>>(x, W, b, out);
}